// Round 17
// baseline (369.604 us; speedup 1.0000x reference)
//
#include <hip/hip_runtime.h>

typedef unsigned short u16;
typedef unsigned int   u32;
typedef unsigned long long u64;
typedef __attribute__((ext_vector_type(8))) __bf16 bf16x8;
typedef __attribute__((ext_vector_type(4))) float   f32x4;

#define MROWS 16400     // 16 * 1025
#define NPADROWS 16512  // padded rows in bf16 buffers
#define KD 1024
#define MATEL ((size_t)NPADROWS * KD)   // elems per padded matrix
#define NT 32           // K-tiles of 32

__device__ __forceinline__ u16 f2b(float f) {
  union { float f; u32 u; } x; x.f = f;
  return (u16)((x.u + 0x7FFFu + ((x.u >> 16) & 1u)) >> 16);
}
__device__ __forceinline__ float b2f(u16 h) {
  union { u32 u; float f; } x; x.u = ((u32)h) << 16;
  return x.f;
}

__device__ __forceinline__ void gll16(const u16* g, u16* l) {
  __builtin_amdgcn_global_load_lds(
      (const __attribute__((address_space(1))) void*)g,
      (__attribute__((address_space(3))) void*)l, 16, 0, 0);
}

// ---------------------------------------------------------------------------
// Merged prologue: blocks [0,4096) transpose+convert weights; blocks
// [4096,6144) convert q/k/v fp32 -> padded bf16 (grid-stride).
// ---------------------------------------------------------------------------
__global__ __launch_bounds__(256) void k_pre(
    const float* __restrict__ W0, const float* __restrict__ W1,
    const float* __restrict__ W2, const float* __restrict__ W3,
    u16* __restrict__ T,
    const float* __restrict__ q, const float* __restrict__ k,
    const float* __restrict__ v, u16* __restrict__ dst)
{
  if (blockIdx.x < 4096) {
    __shared__ float tile[32][33];
    int z = blockIdx.x >> 10;
    int tl = blockIdx.x & 1023;
    int k0 = (tl >> 5) * 32, n0 = (tl & 31) * 32;
    int tx = threadIdx.x & 31, ty = threadIdx.x >> 5;
    const float* W = (z == 0) ? W0 : (z == 1) ? W1 : (z == 2) ? W2 : W3;
    u16* Tz = T + (size_t)z * KD * KD;
#pragma unroll
    for (int r = ty; r < 32; r += 8)
      tile[r][tx] = W[(size_t)(k0 + r) * KD + n0 + tx];
    __syncthreads();
#pragma unroll
    for (int r = ty; r < 32; r += 8)
      Tz[(size_t)(n0 + r) * KD + k0 + tx] = f2b(tile[tx][r]);
  } else {
    int cid = blockIdx.x - 4096;
    const size_t CH_PER_MAT = MATEL / 8;
    const size_t total = 3 * CH_PER_MAT;
    for (size_t c = (size_t)cid * 256 + threadIdx.x; c < total;
         c += (size_t)2048 * 256) {
      size_t z = c / CH_PER_MAT;
      size_t r = c - z * CH_PER_MAT;
      size_t row = r >> 7;
      int col8 = (int)(r & 127) * 8;
      u16* o = dst + z * MATEL + row * KD + col8;
      if (row < MROWS) {
        const float* s = ((z == 0) ? q : (z == 1) ? k : v) + row * KD + col8;
        float4 f0 = *(const float4*)s;
        float4 f1 = *(const float4*)(s + 4);
        ushort4 o0; o0.x = f2b(f0.x); o0.y = f2b(f0.y); o0.z = f2b(f0.z); o0.w = f2b(f0.w);
        ushort4 o1; o1.x = f2b(f1.x); o1.y = f2b(f1.y); o1.z = f2b(f1.z); o1.w = f2b(f1.w);
        *(ushort4*)o = o0; *(ushort4*)(o + 4) = o1;
      } else {
        ushort4 zz; zz.x = zz.y = zz.z = zz.w = 0;
        *(ushort4*)o = zz; *(ushort4*)(o + 4) = zz;
      }
    }
  }
}

// ---------------------------------------------------------------------------
// QKV GEMM (R15, frozen — at the documented K=1024 plain-HIP plateau):
// 256x256 tile, BK=32, 8 waves, 3-buf counted vmcnt(4), quarter-wave swizzle.
// ---------------------------------------------------------------------------
template<bool OUT_FP32>
__global__ __launch_bounds__(512, 1) void k_gemm256(
    const u16* __restrict__ Ab, const u16* __restrict__ Bt,
    u16* __restrict__ Cb, float* __restrict__ Cf,
    const float* __restrict__ bias, int nwg)
{
  __shared__ u16 lds[3 * 16384];

  int lin = blockIdx.x;
  int qq = nwg >> 3, r8 = nwg & 7;
  int xcd = lin & 7, pos = lin >> 3;
  int wg = (xcd < r8 ? xcd * (qq + 1) : r8 * (qq + 1) + (xcd - r8) * qq) + pos;
  int bn = wg & 3;
  int rest = wg >> 2;
  int bm = rest % 65;
  int z  = rest / 65;

  int t = threadIdx.x;
  int w = t >> 6, l = t & 63;
  int lrow = l & 15, kgrp = l >> 4;
  int wrow = w >> 2, wcol = w & 3;

  int pr = t >> 2;
  int ccl = ((t & 3) ^ ((t >> 3) & 3)) * 8;
  int ar0 = bm * 256 + pr;        if (ar0 > NPADROWS - 1) ar0 = NPADROWS - 1;
  int ar1 = bm * 256 + 128 + pr;  if (ar1 > NPADROWS - 1) ar1 = NPADROWS - 1;
  const u16* gA0 = Ab + (size_t)z * MATEL + (size_t)ar0 * KD + ccl;
  const u16* gA1 = Ab + (size_t)z * MATEL + (size_t)ar1 * KD + ccl;
  const u16* gB0 = Bt + (size_t)z * (1024 * 1024) + (size_t)(bn * 256 + pr) * KD + ccl;
  const u16* gB1 = gB0 + (size_t)128 * KD;

  int qr = (lrow >> 1) & 3;
  int xk = (kgrp ^ qr) * 8;

  f32x4 acc[8][4] = {};
  bf16x8 afr[4], bfr2[2];

#define STAGE(B) { u16* L = lds + (B) * 16384;                          \
    gll16(gA0, L + w * 512);          gll16(gA1, L + 4096 + w * 512);   \
    gll16(gB0, L + 8192 + w * 512);   gll16(gB1, L + 12288 + w * 512);  \
    gA0 += 32; gA1 += 32; gB0 += 32; gB1 += 32; }

#define WAITV4 do { __builtin_amdgcn_sched_barrier(0);                  \
    asm volatile("s_waitcnt vmcnt(4)" ::: "memory");                    \
    __builtin_amdgcn_sched_barrier(0); } while (0)
#define WAITV0 do { __builtin_amdgcn_sched_barrier(0);                  \
    asm volatile("s_waitcnt vmcnt(0)" ::: "memory");                    \
    __builtin_amdgcn_sched_barrier(0); } while (0)
#define BAR do { __builtin_amdgcn_sched_barrier(0);                     \
    __builtin_amdgcn_s_barrier();                                       \
    __builtin_amdgcn_sched_barrier(0); } while (0)

#define READ_A(FM0) {                                                   \
    _Pragma("unroll")                                                   \
    for (int qa = 0; qa < 4; ++qa)                                      \
      afr[qa] = *(const bf16x8*)(Lb + (wrow * 128 + (FM0 + qa) * 16 + lrow) * 32 + xk); }
#define READ_B(FN0) {                                                   \
    _Pragma("unroll")                                                   \
    for (int qb = 0; qb < 2; ++qb)                                      \
      bfr2[qb] = *(const bf16x8*)(Lb + 8192 + (wcol * 64 + (FN0 + qb) * 16 + lrow) * 32 + xk); }
#define MFMA_Q(FM0, FN0) {                                              \
    __builtin_amdgcn_s_setprio(1);                                      \
    _Pragma("unroll")                                                   \
    for (int qa = 0; qa < 4; ++qa)                                      \
      _Pragma("unroll")                                                 \
      for (int qb = 0; qb < 2; ++qb)                                    \
        acc[FM0 + qa][FN0 + qb] = __builtin_amdgcn_mfma_f32_16x16x32_bf16( \
            afr[qa], bfr2[qb], acc[FM0 + qa][FN0 + qb], 0, 0, 0);       \
    __builtin_amdgcn_s_setprio(0); }

  STAGE(0); STAGE(1);
  WAITV4;
  BAR;

  int cur = 0;
  for (int kt = 0; kt < NT; ++kt) {
    if (kt + 2 < NT) {
      int pre = cur + 2; if (pre >= 3) pre -= 3;
      STAGE(pre);
    }
    const u16* Lb = lds + cur * 16384;
    READ_A(0); READ_B(0);
    BAR; MFMA_Q(0, 0); BAR;
    READ_B(2);
    BAR; MFMA_Q(0, 2); BAR;
    READ_A(4);
    BAR; MFMA_Q(4, 2); BAR;
    READ_B(0);
    BAR; MFMA_Q(4, 0);
    if (kt + 1 < NT) {
      if (kt + 2 < NT) { WAITV4; }
      else            { WAITV0; }
      BAR;
    }
    cur += 1; if (cur == 3) cur = 0;
  }
#undef STAGE
#undef WAITV4
#undef WAITV0
#undef BAR
#undef READ_A
#undef READ_B
#undef MFMA_Q

#pragma unroll
  for (int fm = 0; fm < 8; ++fm) {
#pragma unroll
    for (int fn = 0; fn < 4; ++fn) {
      int gcol = bn * 256 + wcol * 64 + fn * 16 + lrow;
#pragma unroll
      for (int r = 0; r < 4; ++r) {
        int grow = bm * 256 + wrow * 128 + fm * 16 + kgrp * 4 + r;
        if constexpr (OUT_FP32) {
          if (grow < MROWS)
            Cf[(size_t)grow * KD + gcol] = acc[fm][fn][r] + bias[gcol];
        } else {
          if (grow < NPADROWS)
            Cb[(size_t)z * MATEL + (size_t)grow * KD + gcol] = f2b(acc[fm][fn][r]);
        }
      }
    }
  }
}

// ---------------------------------------------------------------------------
// Out-proj GEMM (R12-verified 128² kernel, FROZEN).
// ---------------------------------------------------------------------------
template<bool OUT_FP32>
__global__ __launch_bounds__(256) void k_gemm(
    const u16* __restrict__ Ab, const u16* __restrict__ Bt,
    u16* __restrict__ Cb, float* __restrict__ Cf,
    const float* __restrict__ bias, int nwg)
{
  __shared__ u16 lds[2 * 8192];

  int lin = blockIdx.x;
  int cpx = nwg >> 3;
  int swz = (lin & 7) * cpx + (lin >> 3);
  int bn = swz & 7;
  int rest = swz >> 3;
  int bm = rest % 129;
  int z  = rest / 129;

  int t = threadIdx.x;
  int w = t >> 6, l = t & 63;
  int lrow = l & 15, kgrp = l >> 4;
  int wm = (w >> 1) * 64, wn = (w & 1) * 64;

  int srow = w * 16 + (l >> 2);
  int scol = ((l & 3) ^ ((srow >> 1) & 3)) * 8;
  const u16* gA  = Ab + (size_t)z * MATEL + (size_t)(bm * 128 + srow) * KD + scol;
  const u16* gA2 = gA + (size_t)64 * KD;
  const u16* gB  = Bt + (size_t)z * (1024 * 1024) + (size_t)(bn * 128 + srow) * KD + scol;
  const u16* gB2 = gB + (size_t)64 * KD;
  int dA0 = w * 512;
  int dA1 = 2048 + w * 512;
  int dB0 = 4096 + w * 512;
  int dB1 = 6144 + w * 512;

  int qr = (lrow >> 1) & 3;
  int aoff[4], boff[4];
#pragma unroll
  for (int fm = 0; fm < 4; ++fm)
    aoff[fm] = (wm + fm * 16 + lrow) * 32 + ((kgrp ^ qr) * 8);
#pragma unroll
  for (int fn = 0; fn < 4; ++fn)
    boff[fn] = 4096 + (wn + fn * 16 + lrow) * 32 + ((kgrp ^ qr) * 8);

  f32x4 acc[4][4] = {};

#define STAGE(B) { u16* L = lds + (B) * 8192;                         \
    gll16(gA,  L + dA0); gll16(gA2, L + dA1);                         \
    gll16(gB,  L + dB0); gll16(gB2, L + dB1);                         \
    gA += 32; gA2 += 32; gB += 32; gB2 += 32; }

  STAGE(0);
  __syncthreads();

  int buf = 0;
#pragma unroll 2
  for (int kt = 0; kt < NT; ++kt) {
    if (kt + 1 < NT) STAGE(buf ^ 1);

    const u16* Lb = lds + buf * 8192;
    bf16x8 af[4], bfr[4];
#pragma unroll
    for (int fm = 0; fm < 4; ++fm)
      af[fm] = *(const bf16x8*)(Lb + aoff[fm]);
#pragma unroll
    for (int fn = 0; fn < 4; ++fn)
      bfr[fn] = *(const bf16x8*)(Lb + boff[fn]);
#pragma unroll
    for (int fm = 0; fm < 4; ++fm)
#pragma unroll
      for (int fn = 0; fn < 4; ++fn)
        acc[fm][fn] = __builtin_amdgcn_mfma_f32_16x16x32_bf16(af[fm], bfr[fn], acc[fm][fn], 0, 0, 0);

    __syncthreads();
    buf ^= 1;
  }
#undef STAGE

#pragma unroll
  for (int fm = 0; fm < 4; ++fm) {
#pragma unroll
    for (int fn = 0; fn < 4; ++fn) {
      int gcol = bn * 128 + wn + fn * 16 + lrow;
#pragma unroll
      for (int r = 0; r < 4; ++r) {
        int grow = bm * 128 + wm + fm * 16 + kgrp * 4 + r;
        if constexpr (OUT_FP32) {
          if (grow < MROWS)
            Cf[(size_t)grow * KD + gcol] = acc[fm][fn][r] + bias[gcol];
        } else {
          Cb[(size_t)z * MATEL + (size_t)grow * KD + gcol] = f2b(acc[fm][fn][r]);
        }
      }
    }
  }
}

// ---------------------------------------------------------------------------
// Merged attention v5: R14/R15 structure + explicit ILP. Blocks [0,256) =
// dense BOS-row attention (first); blocks [256,4352) = 2x2 query-tiled
// nearby attention. Dots: ALL 20 K-loads hoisted into register arrays
// (compile-time indexed, rule-20-safe) BEFORE the FMA loop — ~20 loads in
// flight per thread replaces the ~2 the compiler managed (VGPR 64 -> ~160,
// deliberate ILP-for-TLP trade on a latency-bound gather). PV: V-loads
// chunk-hoisted 8 at a time (fully unrolled, tail guards fold).
// ---------------------------------------------------------------------------
__global__ __launch_bounds__(256) void k_attn(
    const u16* __restrict__ Qp, const u16* __restrict__ Kp,
    const u16* __restrict__ Vp, u16* __restrict__ AO)
{
  int t = threadIdx.x;

  if (blockIdx.x >= 256) {
    __shared__ float sdp[4][16][37];
    __shared__ int   keys[37];
    __shared__ u64   incm[4];

    int bid = blockIdx.x - 256;
    int b = bid >> 8;
    int tile = bid & 255;
    int pi0 = (tile >> 4) * 2, pj0 = (tile & 15) * 2;
    size_t rowbase = (size_t)b * 1025;

    int iq[4];
#pragma unroll
    for (int qi = 0; qi < 4; ++qi)
      iq[qi] = 1 + (pi0 + (qi >> 1)) * 32 + (pj0 + (qi & 1));

    if (t < 37) {
      if (t < 36) {
        int r = pi0 - 2 + t / 6, c = pj0 - 2 + t % 6;
        keys[t] = (r >= 0 && r < 32 && c >= 0 && c < 32) ? (1 + r * 32 + c) : -1;
      } else {
        keys[36] = 0;
      }
    }
    if (t < 4) {
      int di = t >> 1, dj = t & 1;
      u64 m = 1ull << 36;
      for (int j = 0; j < 36; ++j) {
        int wr = j / 6, wc = j % 6;
        if (wr >= di && wr < di + 5 && wc >= dj && wc < dj + 5) m |= 1ull << j;
      }
      incm[t] = m;
    }

    int e = t & 3;
    int hD = (t >> 2) & 15;
    float qreg[4][16];
#pragma unroll
    for (int qi = 0; qi < 4; ++qi) {
      const u16* qp = Qp + (rowbase + iq[qi]) * 1024 + hD * 64 + e * 16;
      uint4 a0 = *(const uint4*)qp;
      uint4 a1 = *(const uint4*)(qp + 8);
      u32 uu[8] = {a0.x, a0.y, a0.z, a0.w, a1.x, a1.y, a1.z, a1.w};
#pragma unroll
      for (int u = 0; u < 8; ++u) {
        qreg[qi][u * 2]     = __uint_as_float(uu[u] << 16);
        qreg[qi][u * 2 + 1] = __uint_as_float(uu[u] & 0xffff0000u);
      }
    }
    __syncthreads();

    // ---- dots: hoist ALL K-loads first (deep MLP), then compute ----
    uint4 kva[10], kvb[10];
#pragma unroll
    for (int p = 0; p < 10; ++p) {
      int idx = p * 64 + (t >> 2);
      int j = idx >> 4; if (j > 36) j = 36;
      int key = keys[j];
      int krow = key < 0 ? 0 : key;
      const u16* kp = Kp + (rowbase + krow) * 1024 + hD * 64 + e * 16;
      kva[p] = *(const uint4*)kp;
      kvb[p] = *(const uint4*)(kp + 8);
    }
#pragma unroll
    for (int p = 0; p < 10; ++p) {
      int idx = p * 64 + (t >> 2);
      int j = idx >> 4; if (j > 36) j = 36;
      int key = keys[j];
      float s0 = 0.f, s1 = 0.f, s2 = 0.f, s3 = 0.f;
      u32 uu[8] = {kva[p].x, kva[p].y, kva[p].z, kva[p].w,
                   kvb[p].x, kvb[p].y, kvb[p].z, kvb[p].w};
#pragma unroll
      for (int u = 0; u < 8; ++u) {
        float lo = __uint_as_float(uu[u] << 16);
        float hi = __uint_as_float(uu[u] & 0xffff0000u);
        s0 += qreg[0][u * 2] * lo + qreg[0][u * 2 + 1] * hi;
        s1 += qreg[1][u * 2] * lo + qreg[1][u * 2 + 1] * hi;
        s2 += qreg[2][u * 2] * lo + qreg[2][u * 2 + 1] * hi;
        s3 += qreg[3][u * 2] * lo + qreg[3][u * 2 + 1] * hi;
      }
      s0 += __shfl_xor(s0, 1); s0 += __shfl_xor(s0, 2);
      s1 += __shfl_xor(s1, 1); s1 += __shfl_xor(s1, 2);
      s2 += __shfl_xor(s2, 1); s2 += __shfl_xor(s2, 2);
      s3 += __shfl_xor(s3, 1); s3 += __shfl_xor(s3, 2);
      if (idx < 592) {
        float sv = (e == 0) ? s0 : (e == 1) ? s1 : (e == 2) ? s2 : s3;
        sdp[e][hD][j] = (key >= 0) ? sv * 0.125f : -3.0e38f;
      }
    }
    __syncthreads();

    { // softmax in place (R13-verified)
      int row = t >> 2;
      int qi = row >> 4, hh = row & 15;
      u64 inc = incm[qi];
      float dv[10];
      float m = -3.0e38f;
#pragma unroll
      for (int s = 0; s < 10; ++s) {
        int j = e + s * 4;
        float d = -3.0e38f;
        if (j < 37) {
          d = sdp[qi][hh][j];
          if (!((inc >> j) & 1)) d = -3.0e38f;
        }
        dv[s] = d;
        m = fmaxf(m, d);
      }
      m = fmaxf(m, __shfl_xor(m, 1));
      m = fmaxf(m, __shfl_xor(m, 2));
      float sum = 0.f;
      float pv[10];
#pragma unroll
      for (int s = 0; s < 10; ++s) {
        int j = e + s * 4;
        float p = (j < 37) ? __expf(dv[s] - m) : 0.f;
        pv[s] = p; sum += p;
      }
      sum += __shfl_xor(sum, 1);
      sum += __shfl_xor(sum, 2);
      float inv = 1.f / sum;
#pragma unroll
      for (int s = 0; s < 10; ++s) {
        int j = e + s * 4;
        if (j < 37) sdp[qi][hh][j] = pv[s] * inv;
      }
    }
    __syncthreads();

    { // PV: chunk-hoisted branch-free V gathers (8 loads in flight)
      int h = t >> 4;
      int c0 = t * 4;
      float a[4][4] = {};
#define PV_CHUNK(J0, CNT) {                                            \
      ushort4 vv[8];                                                   \
      _Pragma("unroll")                                                \
      for (int jj = 0; jj < (CNT); ++jj) {                             \
        int key = keys[(J0) + jj];                                     \
        int krow = key < 0 ? 0 : key;                                  \
        vv[jj] = *(const ushort4*)(Vp + (rowbase + krow) * 1024 + c0); \
      }                                                                \
      _Pragma("unroll")                                                \
      for (int jj = 0; jj < (CNT); ++jj) {                             \
        float v0 = b2f(vv[jj].x), v1 = b2f(vv[jj].y);                  \
        float v2 = b2f(vv[jj].z), v3 = b2f(vv[jj].w);                  \
        _Pragma("unroll")                                              \
        for (int qi = 0; qi < 4; ++qi) {                               \
          float p = sdp[qi][h][(J0) + jj];                             \
          a[qi][0] += p * v0; a[qi][1] += p * v1;                      \
          a[qi][2] += p * v2; a[qi][3] += p * v3;                      \
        }                                                              \
      } }
      PV_CHUNK(0, 8)
      PV_CHUNK(8, 8)
      PV_CHUNK(16, 8)
      PV_CHUNK(24, 8)
      PV_CHUNK(32, 5)
#undef PV_CHUNK
#pragma unroll
      for (int qi = 0; qi < 4; ++qi) {
        ushort4 o;
        o.x = f2b(a[qi][0]); o.y = f2b(a[qi][1]);
        o.z = f2b(a[qi][2]); o.w = f2b(a[qi][3]);
        *(ushort4*)&AO[(rowbase + iq[qi]) * 1024 + c0] = o;
      }
    }
  } else {
    // ---------------- BOS-row dense attention (R14-verified) --------------
    __shared__ float q0[64];
    __shared__ float pr[1025];
    __shared__ float red[256];
    __shared__ float red4[256][4];
    int bid = blockIdx.x;
    int b = bid >> 4, h = bid & 15;
    size_t rowbase = (size_t)b * 1025;

    if (t < 64) q0[t] = b2f(Qp[rowbase * 1024 + h * 64 + t]);
    __syncthreads();

    float lmax = -3.0e38f;
    for (int j = t; j < 1025; j += 256) {
      const u16* kp = Kp + (rowbase + j) * 1024 + h * 64;
      float s = 0.f;
#pragma unroll
      for (int e = 0; e < 64; e += 4) {
        ushort4 kv = *(const ushort4*)(kp + e);
        s += q0[e + 0] * b2f(kv.x) + q0[e + 1] * b2f(kv.y)
           + q0[e + 2] * b2f(kv.z) + q0[e + 3] * b2f(kv.w);
      }
      s *= 0.125f;
      pr[j] = s;
      lmax = fmaxf(lmax, s);
    }
    red[t] = lmax; __syncthreads();
    for (int s = 128; s > 0; s >>= 1) {
      if (t < s) red[t] = fmaxf(red[t], red[t + s]);
      __syncthreads();
    }
    float m = red[0]; __syncthreads();

    float lsum = 0.f;
    for (int j = t; j < 1025; j += 256) {
      float p = __expf(pr[j] - m);
      pr[j] = p; lsum += p;
    }
    red[t] = lsum; __syncthreads();
    for (int s = 128; s > 0; s >>= 1) {
      if (t < s) red[t] += red[t + s];
      __syncthreads();
    }
    float inv = 1.f / red[0]; __syncthreads();

    int g16 = t & 15, grp = t >> 4;
    int c0 = h * 64 + g16 * 4;
    float a0 = 0, a1 = 0, a2 = 0, a3 = 0;
    for (int j = grp; j < 1025; j += 16) {
      float p = pr[j];
      ushort4 vv = *(const ushort4*)(Vp + (rowbase + j) * 1024 + c0);
      a0 += p * b2f(vv.x); a1 += p * b2f(vv.y);
      a2 += p * b2f(vv.z); a3 += p * b2f(vv.w);
    }
    red4[t][0] = a0; red4[t][1] = a1; red4[t][2] = a2; red4[t][3] = a3;
    __syncthreads();
    for (int s = 128; s >= 16; s >>= 1) {
      if (t < s) {
#pragma unroll
        for (int kx = 0; kx < 4; ++kx) red4[t][kx] += red4[t + s][kx];
      }
      __syncthreads();
    }
    if (t < 16) {
      ushort4 o;
      o.x = f2b(red4[t][0] * inv); o.y = f2b(red4[t][1] * inv);
      o.z = f2b(red4[t][2] * inv); o.w = f2b(red4[t][3] * inv);
      *(ushort4*)&AO[rowbase * 1024 + h * 64 + t * 4] = o;
    }
  }
}

// ---------------------------------------------------------------------------
extern "C" void kernel_launch(void* const* d_in, const int* in_sizes, int n_in,
                              void* d_out, int out_size, void* d_ws, size_t ws_size,
                              hipStream_t stream) {
  const float* q  = (const float*)d_in[0];
  const float* k  = (const float*)d_in[1];
  const float* v  = (const float*)d_in[2];
  const float* Wq = (const float*)d_in[3];
  const float* Wk = (const float*)d_in[4];
  const float* Wv = (const float*)d_in[5];
  const float* Wo = (const float*)d_in[6];
  const float* bo = (const float*)d_in[7];
  float* out = (float*)d_out;

  // workspace (u16 units), ~211.3 MB total:
  //   wt:  4M            (Wq^T,Wk^T,Wv^T,Wo^T bf16)
  //   qb:  3*MATEL       (q,k,v converted padded bf16)  [AO aliases qb]
  //   Qp:  3*MATEL       (projected Q,K,V bf16 padded)
  u16* wt = (u16*)d_ws;
  u16* qb = wt + (size_t)4 * 1024 * 1024;
  u16* Qp = qb + 3 * MATEL;
  u16* Kp = Qp + MATEL;
  u16* Vp = Kp + MATEL;
  u16* AO = qb;  // alias: qb dead after projection GEMM

  // merged wtrans (4096 blocks) + convert (2048 virtual blocks)
  k_pre<<<6144, 256, 0, stream>>>(Wq, Wk, Wv, Wo, wt, q, k, v, qb);

  // Q/K/V projections: 65 M-tiles x 4 N-tiles x 3 z = 780 blocks
  k_gemm256<false><<<780, 512, 0, stream>>>(qb, wt, Qp, nullptr, nullptr, 780);

  // merged attention: 256 BOS-row blocks FIRST + 4096 nearby blocks
  k_attn<<<4352, 256, 0, stream>>>(Qp, Kp, Vp, AO);

  // output projection (R12 128² kernel): nwg = 8*129 = 1032
  k_gemm<true><<<1032, 256, 0, stream>>>(AO, wt + (size_t)3 * 1024 * 1024,
                                         nullptr, out, bo, 1032);
}

// Round 18
// 349.396 us; speedup vs baseline: 1.0578x; 1.0578x over previous
//
#include <hip/hip_runtime.h>

typedef unsigned short u16;
typedef unsigned int   u32;
typedef unsigned long long u64;
typedef __attribute__((ext_vector_type(8))) __bf16 bf16x8;
typedef __attribute__((ext_vector_type(4))) float   f32x4;

#define MROWS 16400     // 16 * 1025
#define NPADROWS 16512  // padded rows in bf16 buffers
#define KD 1024
#define MATEL ((size_t)NPADROWS * KD)   // elems per padded matrix
#define NT 32           // K-tiles of 32

__device__ __forceinline__ u16 f2b(float f) {
  union { float f; u32 u; } x; x.f = f;
  return (u16)((x.u + 0x7FFFu + ((x.u >> 16) & 1u)) >> 16);
}
__device__ __forceinline__ float b2f(u16 h) {
  union { u32 u; float f; } x; x.u = ((u32)h) << 16;
  return x.f;
}

__device__ __forceinline__ void gll16(const u16* g, u16* l) {
  __builtin_amdgcn_global_load_lds(
      (const __attribute__((address_space(1))) void*)g,
      (__attribute__((address_space(3))) void*)l, 16, 0, 0);
}

// ---------------------------------------------------------------------------
// Merged prologue: blocks [0,4096) transpose+convert weights; blocks
// [4096,6144) convert q/k/v fp32 -> padded bf16 (grid-stride).
// ---------------------------------------------------------------------------
__global__ __launch_bounds__(256) void k_pre(
    const float* __restrict__ W0, const float* __restrict__ W1,
    const float* __restrict__ W2, const float* __restrict__ W3,
    u16* __restrict__ T,
    const float* __restrict__ q, const float* __restrict__ k,
    const float* __restrict__ v, u16* __restrict__ dst)
{
  if (blockIdx.x < 4096) {
    __shared__ float tile[32][33];
    int z = blockIdx.x >> 10;
    int tl = blockIdx.x & 1023;
    int k0 = (tl >> 5) * 32, n0 = (tl & 31) * 32;
    int tx = threadIdx.x & 31, ty = threadIdx.x >> 5;
    const float* W = (z == 0) ? W0 : (z == 1) ? W1 : (z == 2) ? W2 : W3;
    u16* Tz = T + (size_t)z * KD * KD;
#pragma unroll
    for (int r = ty; r < 32; r += 8)
      tile[r][tx] = W[(size_t)(k0 + r) * KD + n0 + tx];
    __syncthreads();
#pragma unroll
    for (int r = ty; r < 32; r += 8)
      Tz[(size_t)(n0 + r) * KD + k0 + tx] = f2b(tile[tx][r]);
  } else {
    int cid = blockIdx.x - 4096;
    const size_t CH_PER_MAT = MATEL / 8;
    const size_t total = 3 * CH_PER_MAT;
    for (size_t c = (size_t)cid * 256 + threadIdx.x; c < total;
         c += (size_t)2048 * 256) {
      size_t z = c / CH_PER_MAT;
      size_t r = c - z * CH_PER_MAT;
      size_t row = r >> 7;
      int col8 = (int)(r & 127) * 8;
      u16* o = dst + z * MATEL + row * KD + col8;
      if (row < MROWS) {
        const float* s = ((z == 0) ? q : (z == 1) ? k : v) + row * KD + col8;
        float4 f0 = *(const float4*)s;
        float4 f1 = *(const float4*)(s + 4);
        ushort4 o0; o0.x = f2b(f0.x); o0.y = f2b(f0.y); o0.z = f2b(f0.z); o0.w = f2b(f0.w);
        ushort4 o1; o1.x = f2b(f1.x); o1.y = f2b(f1.y); o1.z = f2b(f1.z); o1.w = f2b(f1.w);
        *(ushort4*)o = o0; *(ushort4*)(o + 4) = o1;
      } else {
        ushort4 zz; zz.x = zz.y = zz.z = zz.w = 0;
        *(ushort4*)o = zz; *(ushort4*)(o + 4) = zz;
      }
    }
  }
}

// ---------------------------------------------------------------------------
// QKV GEMM (R15, frozen — at the documented K=1024 plain-HIP plateau):
// 256x256 tile, BK=32, 8 waves, 3-buf counted vmcnt(4), quarter-wave swizzle.
// ---------------------------------------------------------------------------
template<bool OUT_FP32>
__global__ __launch_bounds__(512, 1) void k_gemm256(
    const u16* __restrict__ Ab, const u16* __restrict__ Bt,
    u16* __restrict__ Cb, float* __restrict__ Cf,
    const float* __restrict__ bias, int nwg)
{
  __shared__ u16 lds[3 * 16384];

  int lin = blockIdx.x;
  int qq = nwg >> 3, r8 = nwg & 7;
  int xcd = lin & 7, pos = lin >> 3;
  int wg = (xcd < r8 ? xcd * (qq + 1) : r8 * (qq + 1) + (xcd - r8) * qq) + pos;
  int bn = wg & 3;
  int rest = wg >> 2;
  int bm = rest % 65;
  int z  = rest / 65;

  int t = threadIdx.x;
  int w = t >> 6, l = t & 63;
  int lrow = l & 15, kgrp = l >> 4;
  int wrow = w >> 2, wcol = w & 3;

  int pr = t >> 2;
  int ccl = ((t & 3) ^ ((t >> 3) & 3)) * 8;
  int ar0 = bm * 256 + pr;        if (ar0 > NPADROWS - 1) ar0 = NPADROWS - 1;
  int ar1 = bm * 256 + 128 + pr;  if (ar1 > NPADROWS - 1) ar1 = NPADROWS - 1;
  const u16* gA0 = Ab + (size_t)z * MATEL + (size_t)ar0 * KD + ccl;
  const u16* gA1 = Ab + (size_t)z * MATEL + (size_t)ar1 * KD + ccl;
  const u16* gB0 = Bt + (size_t)z * (1024 * 1024) + (size_t)(bn * 256 + pr) * KD + ccl;
  const u16* gB1 = gB0 + (size_t)128 * KD;

  int qr = (lrow >> 1) & 3;
  int xk = (kgrp ^ qr) * 8;

  f32x4 acc[8][4] = {};
  bf16x8 afr[4], bfr2[2];

#define STAGE(B) { u16* L = lds + (B) * 16384;                          \
    gll16(gA0, L + w * 512);          gll16(gA1, L + 4096 + w * 512);   \
    gll16(gB0, L + 8192 + w * 512);   gll16(gB1, L + 12288 + w * 512);  \
    gA0 += 32; gA1 += 32; gB0 += 32; gB1 += 32; }

#define WAITV4 do { __builtin_amdgcn_sched_barrier(0);                  \
    asm volatile("s_waitcnt vmcnt(4)" ::: "memory");                    \
    __builtin_amdgcn_sched_barrier(0); } while (0)
#define WAITV0 do { __builtin_amdgcn_sched_barrier(0);                  \
    asm volatile("s_waitcnt vmcnt(0)" ::: "memory");                    \
    __builtin_amdgcn_sched_barrier(0); } while (0)
#define BAR do { __builtin_amdgcn_sched_barrier(0);                     \
    __builtin_amdgcn_s_barrier();                                       \
    __builtin_amdgcn_sched_barrier(0); } while (0)

#define READ_A(FM0) {                                                   \
    _Pragma("unroll")                                                   \
    for (int qa = 0; qa < 4; ++qa)                                      \
      afr[qa] = *(const bf16x8*)(Lb + (wrow * 128 + (FM0 + qa) * 16 + lrow) * 32 + xk); }
#define READ_B(FN0) {                                                   \
    _Pragma("unroll")                                                   \
    for (int qb = 0; qb < 2; ++qb)                                      \
      bfr2[qb] = *(const bf16x8*)(Lb + 8192 + (wcol * 64 + (FN0 + qb) * 16 + lrow) * 32 + xk); }
#define MFMA_Q(FM0, FN0) {                                              \
    __builtin_amdgcn_s_setprio(1);                                      \
    _Pragma("unroll")                                                   \
    for (int qa = 0; qa < 4; ++qa)                                      \
      _Pragma("unroll")                                                 \
      for (int qb = 0; qb < 2; ++qb)                                    \
        acc[FM0 + qa][FN0 + qb] = __builtin_amdgcn_mfma_f32_16x16x32_bf16( \
            afr[qa], bfr2[qb], acc[FM0 + qa][FN0 + qb], 0, 0, 0);       \
    __builtin_amdgcn_s_setprio(0); }

  STAGE(0); STAGE(1);
  WAITV4;
  BAR;

  int cur = 0;
  for (int kt = 0; kt < NT; ++kt) {
    if (kt + 2 < NT) {
      int pre = cur + 2; if (pre >= 3) pre -= 3;
      STAGE(pre);
    }
    const u16* Lb = lds + cur * 16384;
    READ_A(0); READ_B(0);
    BAR; MFMA_Q(0, 0); BAR;
    READ_B(2);
    BAR; MFMA_Q(0, 2); BAR;
    READ_A(4);
    BAR; MFMA_Q(4, 2); BAR;
    READ_B(0);
    BAR; MFMA_Q(4, 0);
    if (kt + 1 < NT) {
      if (kt + 2 < NT) { WAITV4; }
      else            { WAITV0; }
      BAR;
    }
    cur += 1; if (cur == 3) cur = 0;
  }
#undef STAGE
#undef WAITV4
#undef WAITV0
#undef BAR
#undef READ_A
#undef READ_B
#undef MFMA_Q

#pragma unroll
  for (int fm = 0; fm < 8; ++fm) {
#pragma unroll
    for (int fn = 0; fn < 4; ++fn) {
      int gcol = bn * 256 + wcol * 64 + fn * 16 + lrow;
#pragma unroll
      for (int r = 0; r < 4; ++r) {
        int grow = bm * 256 + wrow * 128 + fm * 16 + kgrp * 4 + r;
        if constexpr (OUT_FP32) {
          if (grow < MROWS)
            Cf[(size_t)grow * KD + gcol] = acc[fm][fn][r] + bias[gcol];
        } else {
          if (grow < NPADROWS)
            Cb[(size_t)z * MATEL + (size_t)grow * KD + gcol] = f2b(acc[fm][fn][r]);
        }
      }
    }
  }
}

// ---------------------------------------------------------------------------
// Out-proj GEMM (R12-verified 128² kernel, FROZEN).
// ---------------------------------------------------------------------------
template<bool OUT_FP32>
__global__ __launch_bounds__(256) void k_gemm(
    const u16* __restrict__ Ab, const u16* __restrict__ Bt,
    u16* __restrict__ Cb, float* __restrict__ Cf,
    const float* __restrict__ bias, int nwg)
{
  __shared__ u16 lds[2 * 8192];

  int lin = blockIdx.x;
  int cpx = nwg >> 3;
  int swz = (lin & 7) * cpx + (lin >> 3);
  int bn = swz & 7;
  int rest = swz >> 3;
  int bm = rest % 129;
  int z  = rest / 129;

  int t = threadIdx.x;
  int w = t >> 6, l = t & 63;
  int lrow = l & 15, kgrp = l >> 4;
  int wm = (w >> 1) * 64, wn = (w & 1) * 64;

  int srow = w * 16 + (l >> 2);
  int scol = ((l & 3) ^ ((srow >> 1) & 3)) * 8;
  const u16* gA  = Ab + (size_t)z * MATEL + (size_t)(bm * 128 + srow) * KD + scol;
  const u16* gA2 = gA + (size_t)64 * KD;
  const u16* gB  = Bt + (size_t)z * (1024 * 1024) + (size_t)(bn * 128 + srow) * KD + scol;
  const u16* gB2 = gB + (size_t)64 * KD;
  int dA0 = w * 512;
  int dA1 = 2048 + w * 512;
  int dB0 = 4096 + w * 512;
  int dB1 = 6144 + w * 512;

  int qr = (lrow >> 1) & 3;
  int aoff[4], boff[4];
#pragma unroll
  for (int fm = 0; fm < 4; ++fm)
    aoff[fm] = (wm + fm * 16 + lrow) * 32 + ((kgrp ^ qr) * 8);
#pragma unroll
  for (int fn = 0; fn < 4; ++fn)
    boff[fn] = 4096 + (wn + fn * 16 + lrow) * 32 + ((kgrp ^ qr) * 8);

  f32x4 acc[4][4] = {};

#define STAGE(B) { u16* L = lds + (B) * 8192;                         \
    gll16(gA,  L + dA0); gll16(gA2, L + dA1);                         \
    gll16(gB,  L + dB0); gll16(gB2, L + dB1);                         \
    gA += 32; gA2 += 32; gB += 32; gB2 += 32; }

  STAGE(0);
  __syncthreads();

  int buf = 0;
#pragma unroll 2
  for (int kt = 0; kt < NT; ++kt) {
    if (kt + 1 < NT) STAGE(buf ^ 1);

    const u16* Lb = lds + buf * 8192;
    bf16x8 af[4], bfr[4];
#pragma unroll
    for (int fm = 0; fm < 4; ++fm)
      af[fm] = *(const bf16x8*)(Lb + aoff[fm]);
#pragma unroll
    for (int fn = 0; fn < 4; ++fn)
      bfr[fn] = *(const bf16x8*)(Lb + boff[fn]);
#pragma unroll
    for (int fm = 0; fm < 4; ++fm)
#pragma unroll
      for (int fn = 0; fn < 4; ++fn)
        acc[fm][fn] = __builtin_amdgcn_mfma_f32_16x16x32_bf16(af[fm], bfr[fn], acc[fm][fn], 0, 0, 0);

    __syncthreads();
    buf ^= 1;
  }
#undef STAGE

#pragma unroll
  for (int fm = 0; fm < 4; ++fm) {
#pragma unroll
    for (int fn = 0; fn < 4; ++fn) {
      int gcol = bn * 128 + wn + fn * 16 + lrow;
#pragma unroll
      for (int r = 0; r < 4; ++r) {
        int grow = bm * 128 + wm + fm * 16 + kgrp * 4 + r;
        if constexpr (OUT_FP32) {
          if (grow < MROWS)
            Cf[(size_t)grow * KD + gcol] = acc[fm][fn][r] + bias[gcol];
        } else {
          Cb[(size_t)z * MATEL + (size_t)grow * KD + gcol] = f2b(acc[fm][fn][r]);
        }
      }
    }
  }
}

// ---------------------------------------------------------------------------
// Merged attention (R14/R15-verified, FROZEN): blocks [0,256) = dense BOS-row
// attention first; blocks [256,4352) = 2x2 query-tiled nearby attention with
// branch-free gathers.
// ---------------------------------------------------------------------------
__global__ __launch_bounds__(256) void k_attn(
    const u16* __restrict__ Qp, const u16* __restrict__ Kp,
    const u16* __restrict__ Vp, u16* __restrict__ AO)
{
  int t = threadIdx.x;

  if (blockIdx.x >= 256) {
    __shared__ float sdp[4][16][37];
    __shared__ int   keys[37];
    __shared__ u64   incm[4];

    int bid = blockIdx.x - 256;
    int b = bid >> 8;
    int tile = bid & 255;
    int pi0 = (tile >> 4) * 2, pj0 = (tile & 15) * 2;
    size_t rowbase = (size_t)b * 1025;

    int iq[4];
#pragma unroll
    for (int qi = 0; qi < 4; ++qi)
      iq[qi] = 1 + (pi0 + (qi >> 1)) * 32 + (pj0 + (qi & 1));

    if (t < 37) {
      if (t < 36) {
        int r = pi0 - 2 + t / 6, c = pj0 - 2 + t % 6;
        keys[t] = (r >= 0 && r < 32 && c >= 0 && c < 32) ? (1 + r * 32 + c) : -1;
      } else {
        keys[36] = 0;
      }
    }
    if (t < 4) {
      int di = t >> 1, dj = t & 1;
      u64 m = 1ull << 36;
      for (int j = 0; j < 36; ++j) {
        int wr = j / 6, wc = j % 6;
        if (wr >= di && wr < di + 5 && wc >= dj && wc < dj + 5) m |= 1ull << j;
      }
      incm[t] = m;
    }

    int e = t & 3;
    int hD = (t >> 2) & 15;
    float qreg[4][16];
#pragma unroll
    for (int qi = 0; qi < 4; ++qi) {
      const u16* qp = Qp + (rowbase + iq[qi]) * 1024 + hD * 64 + e * 16;
      uint4 a0 = *(const uint4*)qp;
      uint4 a1 = *(const uint4*)(qp + 8);
      u32 uu[8] = {a0.x, a0.y, a0.z, a0.w, a1.x, a1.y, a1.z, a1.w};
#pragma unroll
      for (int u = 0; u < 8; ++u) {
        qreg[qi][u * 2]     = __uint_as_float(uu[u] << 16);
        qreg[qi][u * 2 + 1] = __uint_as_float(uu[u] & 0xffff0000u);
      }
    }
    __syncthreads();

#pragma unroll
    for (int p = 0; p < 10; ++p) {
      int idx = p * 64 + (t >> 2);
      int j = idx >> 4; if (j > 36) j = 36;
      int key = keys[j];
      int krow = key < 0 ? 0 : key;
      const u16* kp = Kp + (rowbase + krow) * 1024 + hD * 64 + e * 16;
      uint4 kv0 = *(const uint4*)kp;
      uint4 kv1 = *(const uint4*)(kp + 8);
      float s0 = 0.f, s1 = 0.f, s2 = 0.f, s3 = 0.f;
      u32 uu[8] = {kv0.x, kv0.y, kv0.z, kv0.w, kv1.x, kv1.y, kv1.z, kv1.w};
#pragma unroll
      for (int u = 0; u < 8; ++u) {
        float lo = __uint_as_float(uu[u] << 16);
        float hi = __uint_as_float(uu[u] & 0xffff0000u);
        s0 += qreg[0][u * 2] * lo + qreg[0][u * 2 + 1] * hi;
        s1 += qreg[1][u * 2] * lo + qreg[1][u * 2 + 1] * hi;
        s2 += qreg[2][u * 2] * lo + qreg[2][u * 2 + 1] * hi;
        s3 += qreg[3][u * 2] * lo + qreg[3][u * 2 + 1] * hi;
      }
      s0 += __shfl_xor(s0, 1); s0 += __shfl_xor(s0, 2);
      s1 += __shfl_xor(s1, 1); s1 += __shfl_xor(s1, 2);
      s2 += __shfl_xor(s2, 1); s2 += __shfl_xor(s2, 2);
      s3 += __shfl_xor(s3, 1); s3 += __shfl_xor(s3, 2);
      if (idx < 592) {
        float sv = (e == 0) ? s0 : (e == 1) ? s1 : (e == 2) ? s2 : s3;
        sdp[e][hD][j] = (key >= 0) ? sv * 0.125f : -3.0e38f;
      }
    }
    __syncthreads();

    {
      int row = t >> 2;
      int qi = row >> 4, hh = row & 15;
      u64 inc = incm[qi];
      float dv[10];
      float m = -3.0e38f;
#pragma unroll
      for (int s = 0; s < 10; ++s) {
        int j = e + s * 4;
        float d = -3.0e38f;
        if (j < 37) {
          d = sdp[qi][hh][j];
          if (!((inc >> j) & 1)) d = -3.0e38f;
        }
        dv[s] = d;
        m = fmaxf(m, d);
      }
      m = fmaxf(m, __shfl_xor(m, 1));
      m = fmaxf(m, __shfl_xor(m, 2));
      float sum = 0.f;
      float pv[10];
#pragma unroll
      for (int s = 0; s < 10; ++s) {
        int j = e + s * 4;
        float p = (j < 37) ? __expf(dv[s] - m) : 0.f;
        pv[s] = p; sum += p;
      }
      sum += __shfl_xor(sum, 1);
      sum += __shfl_xor(sum, 2);
      float inv = 1.f / sum;
#pragma unroll
      for (int s = 0; s < 10; ++s) {
        int j = e + s * 4;
        if (j < 37) sdp[qi][hh][j] = pv[s] * inv;
      }
    }
    __syncthreads();

    {
      int h = t >> 4;
      int c0 = t * 4;
      float a[4][4] = {};
#pragma unroll 4
      for (int j = 0; j < 37; ++j) {
        int key = keys[j];
        int krow = key < 0 ? 0 : key;
        ushort4 vv = *(const ushort4*)(Vp + (rowbase + krow) * 1024 + c0);
        float v0 = b2f(vv.x), v1 = b2f(vv.y), v2 = b2f(vv.z), v3 = b2f(vv.w);
#pragma unroll
        for (int qi = 0; qi < 4; ++qi) {
          float p = sdp[qi][h][j];
          a[qi][0] += p * v0; a[qi][1] += p * v1;
          a[qi][2] += p * v2; a[qi][3] += p * v3;
        }
      }
#pragma unroll
      for (int qi = 0; qi < 4; ++qi) {
        ushort4 o;
        o.x = f2b(a[qi][0]); o.y = f2b(a[qi][1]);
        o.z = f2b(a[qi][2]); o.w = f2b(a[qi][3]);
        *(ushort4*)&AO[(rowbase + iq[qi]) * 1024 + c0] = o;
      }
    }
  } else {
    __shared__ float q0[64];
    __shared__ float pr[1025];
    __shared__ float red[256];
    __shared__ float red4[256][4];
    int bid = blockIdx.x;
    int b = bid >> 4, h = bid & 15;
    size_t rowbase = (size_t)b * 1025;

    if (t < 64) q0[t] = b2f(Qp[rowbase * 1024 + h * 64 + t]);
    __syncthreads();

    float lmax = -3.0e38f;
    for (int j = t; j < 1025; j += 256) {
      const u16* kp = Kp + (rowbase + j) * 1024 + h * 64;
      float s = 0.f;
#pragma unroll
      for (int e = 0; e < 64; e += 4) {
        ushort4 kv = *(const ushort4*)(kp + e);
        s += q0[e + 0] * b2f(kv.x) + q0[e + 1] * b2f(kv.y)
           + q0[e + 2] * b2f(kv.z) + q0[e + 3] * b2f(kv.w);
      }
      s *= 0.125f;
      pr[j] = s;
      lmax = fmaxf(lmax, s);
    }
    red[t] = lmax; __syncthreads();
    for (int s = 128; s > 0; s >>= 1) {
      if (t < s) red[t] = fmaxf(red[t], red[t + s]);
      __syncthreads();
    }
    float m = red[0]; __syncthreads();

    float lsum = 0.f;
    for (int j = t; j < 1025; j += 256) {
      float p = __expf(pr[j] - m);
      pr[j] = p; lsum += p;
    }
    red[t] = lsum; __syncthreads();
    for (int s = 128; s > 0; s >>= 1) {
      if (t < s) red[t] += red[t + s];
      __syncthreads();
    }
    float inv = 1.f / red[0]; __syncthreads();

    int g16 = t & 15, grp = t >> 4;
    int c0 = h * 64 + g16 * 4;
    float a0 = 0, a1 = 0, a2 = 0, a3 = 0;
    for (int j = grp; j < 1025; j += 16) {
      float p = pr[j];
      ushort4 vv = *(const ushort4*)(Vp + (rowbase + j) * 1024 + c0);
      a0 += p * b2f(vv.x); a1 += p * b2f(vv.y);
      a2 += p * b2f(vv.z); a3 += p * b2f(vv.w);
    }
    red4[t][0] = a0; red4[t][1] = a1; red4[t][2] = a2; red4[t][3] = a3;
    __syncthreads();
    for (int s = 128; s >= 16; s >>= 1) {
      if (t < s) {
#pragma unroll
        for (int kx = 0; kx < 4; ++kx) red4[t][kx] += red4[t + s][kx];
      }
      __syncthreads();
    }
    if (t < 16) {
      ushort4 o;
      o.x = f2b(red4[t][0] * inv); o.y = f2b(red4[t][1] * inv);
      o.z = f2b(red4[t][2] * inv); o.w = f2b(red4[t][3] * inv);
      *(ushort4*)&AO[rowbase * 1024 + h * 64 + t * 4] = o;
    }
  }
}

// ---------------------------------------------------------------------------
extern "C" void kernel_launch(void* const* d_in, const int* in_sizes, int n_in,
                              void* d_out, int out_size, void* d_ws, size_t ws_size,
                              hipStream_t stream) {
  const float* q  = (const float*)d_in[0];
  const float* k  = (const float*)d_in[1];
  const float* v  = (const float*)d_in[2];
  const float* Wq = (const float*)d_in[3];
  const float* Wk = (const float*)d_in[4];
  const float* Wv = (const float*)d_in[5];
  const float* Wo = (const float*)d_in[6];
  const float* bo = (const float*)d_in[7];
  float* out = (float*)d_out;

  // workspace (u16 units), ~211.3 MB total:
  //   wt:  4M            (Wq^T,Wk^T,Wv^T,Wo^T bf16)
  //   qb:  3*MATEL       (q,k,v converted padded bf16)  [AO aliases qb]
  //   Qp:  3*MATEL       (projected Q,K,V bf16 padded)
  u16* wt = (u16*)d_ws;
  u16* qb = wt + (size_t)4 * 1024 * 1024;
  u16* Qp = qb + 3 * MATEL;
  u16* Kp = Qp + MATEL;
  u16* Vp = Kp + MATEL;
  u16* AO = qb;  // alias: qb dead after projection GEMM

  // merged wtrans (4096 blocks) + convert (2048 virtual blocks)
  k_pre<<<6144, 256, 0, stream>>>(Wq, Wk, Wv, Wo, wt, q, k, v, qb);

  // Q/K/V projections: 65 M-tiles x 4 N-tiles x 3 z = 780 blocks
  k_gemm256<false><<<780, 512, 0, stream>>>(qb, wt, Qp, nullptr, nullptr, 780);

  // merged attention: 256 BOS-row blocks FIRST + 4096 nearby blocks
  k_attn<<<4352, 256, 0, stream>>>(Qp, Kp, Vp, AO);

  // output projection (R12 128² kernel): nwg = 8*129 = 1032
  k_gemm<true><<<1032, 256, 0, stream>>>(AO, wt + (size_t)3 * 1024 * 1024,
                                         nullptr, out, bo, 1032);
}